// Round 2
// baseline (923.974 us; speedup 1.0000x reference)
//
#include <hip/hip_runtime.h>
#include <stdint.h>

#define TOKENS 2048
#define HIDDEN 2048
#define INTER  1408
#define NEXP   16
#define BK     64
#define ROWU   64   // ushorts per LDS row (= BK), 128 B row stride

using bf16x8 = __attribute__((ext_vector_type(8))) __bf16;
using f32x4  = __attribute__((ext_vector_type(4))) float;

__device__ __forceinline__ unsigned short bf16bits(float f) {
    union { __bf16 h; unsigned short u; } cv;
    cv.h = (__bf16)f;
    return cv.u;
}

__device__ __forceinline__ void pack8(const float* s, void* dst) {
    bf16x8 v;
#pragma unroll
    for (int j = 0; j < 8; j++) v[j] = (__bf16)s[j];
    *(bf16x8*)dst = v;
}

// ---------------- router: logits -> sigmoid -> top2 -> expert lists; also x -> bf16 ----------------
__global__ __launch_bounds__(64) void router_kernel(
    const float* __restrict__ x, const float* __restrict__ wg,
    int* __restrict__ cnt, int* __restrict__ tok, float* __restrict__ wts,
    unsigned short* __restrict__ xbf)
{
    const int t = blockIdx.x;
    const int lane = threadIdx.x;
    float acc[NEXP];
#pragma unroll
    for (int e = 0; e < NEXP; e++) acc[e] = 0.f;
    const float* xr = x + (size_t)t * HIDDEN;
    unsigned short* xbr = xbf + (size_t)t * HIDDEN;
    for (int h = lane; h < HIDDEN; h += 64) {
        const float xv = xr[h];
        xbr[h] = bf16bits(xv);
        const float* wr = wg + (size_t)h * NEXP;
#pragma unroll
        for (int e = 0; e < NEXP; e++) acc[e] += xv * wr[e];
    }
#pragma unroll
    for (int off = 32; off > 0; off >>= 1) {
#pragma unroll
        for (int e = 0; e < NEXP; e++) acc[e] += __shfl_down(acc[e], off, 64);
    }
    if (lane == 0) {
        float s[NEXP];
#pragma unroll
        for (int e = 0; e < NEXP; e++) s[e] = 1.f / (1.f + __expf(-acc[e]));
        int i0 = 0;
#pragma unroll
        for (int e = 1; e < NEXP; e++) if (s[e] > s[i0]) i0 = e;
        int i1 = (i0 == 0) ? 1 : 0;
#pragma unroll
        for (int e = 0; e < NEXP; e++) if (e != i0 && s[e] > s[i1]) i1 = e;
        float w0 = s[i0], w1 = s[i1];
        const float inv = 1.f / (w0 + w1);
        w0 *= inv; w1 *= inv;
        const int s0 = atomicAdd(&cnt[i0], 1);
        tok[i0 * TOKENS + s0] = t * 2;
        wts[i0 * TOKENS + s0] = w0;
        const int s1 = atomicAdd(&cnt[i1], 1);
        tok[i1 * TOKENS + s1] = t * 2 + 1;
        wts[i1 * TOKENS + s1] = w1;
    }
}

// ---------------- gemm1: h = silu(Xe @ Wg) * (Xe @ Wu), bf16 out ----------------
// grid: (INTER/64, TOKENS/128, NEXP), block 256. BM=128 BN=64 BK=64.
__global__ __launch_bounds__(256) void gemm1_kernel(
    const unsigned short* __restrict__ xbf, const float* __restrict__ wgp,
    const float* __restrict__ wup, const int* __restrict__ cnt,
    const int* __restrict__ tok, unsigned short* __restrict__ hbuf)
{
    const int e = blockIdx.z;
    const int ne = cnt[e];
    const int m0 = blockIdx.y * 128;
    if (m0 >= ne) return;
    const int n0 = blockIdx.x * 64;

    __shared__ __align__(16) unsigned short As[128 * ROWU];
    __shared__ __align__(16) unsigned short Bs[2][64 * ROWU];
    __shared__ int rowp[128];

    const int tid = threadIdx.x;
    if (tid < 128) {
        const int slot = m0 + tid;
        rowp[tid] = tok[e * TOKENS + (slot < ne ? slot : ne - 1)];
    }
    __syncthreads();

    const int lane = tid & 63;
    const int wid  = tid >> 6;
    const int wm = (wid >> 1) * 64;
    const int wn = (wid & 1) * 32;
    const int lr = lane & 15;
    const int lq = lane >> 4;

    // A staging: 4 chunks/thread, row r_i = (tid>>3)+i*32, chunk c = tid&7
    const int ar = tid >> 3;
    const int ac = tid & 7;
    const int apx = ac ^ (ar & 7);           // swizzled chunk (constant: i*32 ≡ 0 mod 8)
    const unsigned short* aptr[4];
#pragma unroll
    for (int i = 0; i < 4; i++)
        aptr[i] = xbf + (size_t)(rowp[ar + i * 32] >> 1) * HIDDEN + ac * 8;

    // B staging: per matrix 2 chunks/thread: c_i = i*4+wid, n = lane
    const float* bptr[2];
    bptr[0] = wgp + (size_t)e * HIDDEN * INTER + n0 + lane;
    bptr[1] = wup + (size_t)e * HIDDEN * INTER + n0 + lane;

    f32x4 accg[4][2], accu[4][2];
    const f32x4 z4 = {0.f, 0.f, 0.f, 0.f};
#pragma unroll
    for (int a = 0; a < 4; a++)
#pragma unroll
        for (int b = 0; b < 2; b++) { accg[a][b] = z4; accu[a][b] = z4; }

    uint4 pa[4];
    float pb[2][2][8];

    auto loadAB = [&](int k0) {
#pragma unroll
        for (int i = 0; i < 4; i++) pa[i] = *(const uint4*)(aptr[i] + k0);
#pragma unroll
        for (int m = 0; m < 2; m++)
#pragma unroll
            for (int i = 0; i < 2; i++) {
                const int c = i * 4 + wid;
                const float* src = bptr[m] + (size_t)(k0 + c * 8) * INTER;
#pragma unroll
                for (int j = 0; j < 8; j++) pb[m][i][j] = src[(size_t)j * INTER];
            }
    };

    loadAB(0);
    for (int k0 = 0; k0 < HIDDEN; k0 += BK) {
        // write staged tile k0 to LDS (compiler inserts vmcnt wait here)
#pragma unroll
        for (int i = 0; i < 4; i++)
            *(uint4*)&As[(ar + i * 32) * ROWU + apx * 8] = pa[i];
#pragma unroll
        for (int m = 0; m < 2; m++)
#pragma unroll
            for (int i = 0; i < 2; i++) {
                const int c = i * 4 + wid;
                pack8(pb[m][i], &Bs[m][lane * ROWU + (c ^ (lane & 7)) * 8]);
            }
        __syncthreads();
        if (k0 + BK < HIDDEN) loadAB(k0 + BK);   // prefetch overlaps MFMA below

#pragma unroll
        for (int ks = 0; ks < 2; ks++) {
            bf16x8 af[4], bg[2], bu[2];
#pragma unroll
            for (int tm = 0; tm < 4; tm++)
                af[tm] = *(const bf16x8*)&As[(wm + tm * 16 + lr) * ROWU + ((ks * 4 + lq) ^ (lr & 7)) * 8];
#pragma unroll
            for (int tn = 0; tn < 2; tn++) {
                const int off = (wn + tn * 16 + lr) * ROWU + ((ks * 4 + lq) ^ (lr & 7)) * 8;
                bg[tn] = *(const bf16x8*)&Bs[0][off];
                bu[tn] = *(const bf16x8*)&Bs[1][off];
            }
#pragma unroll
            for (int tm = 0; tm < 4; tm++)
#pragma unroll
                for (int tn = 0; tn < 2; tn++) {
                    accg[tm][tn] = __builtin_amdgcn_mfma_f32_16x16x32_bf16(af[tm], bg[tn], accg[tm][tn], 0, 0, 0);
                    accu[tm][tn] = __builtin_amdgcn_mfma_f32_16x16x32_bf16(af[tm], bu[tn], accu[tm][tn], 0, 0, 0);
                }
        }
        __syncthreads();
    }

    // epilogue: h = silu(g)*u -> bf16, scattered by pair id
#pragma unroll
    for (int tm = 0; tm < 4; tm++)
#pragma unroll
        for (int tn = 0; tn < 2; tn++)
#pragma unroll
            for (int r = 0; r < 4; r++) {
                const int rowL = wm + tm * 16 + lq * 4 + r;
                const int slot = m0 + rowL;
                if (slot < ne) {
                    const int p = rowp[rowL];
                    const int col = n0 + wn + tn * 16 + lr;
                    const float g = accg[tm][tn][r];
                    const float u = accu[tm][tn][r];
                    const float hv = g * u / (1.f + __expf(-g));
                    hbuf[(size_t)p * INTER + col] = bf16bits(hv);
                }
            }
}

// ---------------- gemm2: out[t] += w * (h_e @ Wd[e]) ----------------
// grid: (HIDDEN/64, TOKENS/128, NEXP), block 256. BM=128 BN=64 BK=64, K=1408.
__global__ __launch_bounds__(256) void gemm2_kernel(
    const unsigned short* __restrict__ hbuf, const float* __restrict__ wdp,
    const int* __restrict__ cnt, const int* __restrict__ tok,
    const float* __restrict__ wts, float* __restrict__ out)
{
    const int e = blockIdx.z;
    const int ne = cnt[e];
    const int m0 = blockIdx.y * 128;
    if (m0 >= ne) return;
    const int n0 = blockIdx.x * 64;

    __shared__ __align__(16) unsigned short As[128 * ROWU];
    __shared__ __align__(16) unsigned short Bs[64 * ROWU];
    __shared__ int rowp[128];
    __shared__ float roww[128];

    const int tid = threadIdx.x;
    if (tid < 128) {
        const int slot = m0 + tid;
        const int cs = slot < ne ? slot : ne - 1;
        rowp[tid] = tok[e * TOKENS + cs];
        roww[tid] = wts[e * TOKENS + cs];
    }
    __syncthreads();

    const int lane = tid & 63;
    const int wid  = tid >> 6;
    const int wm = (wid >> 1) * 64;
    const int wn = (wid & 1) * 32;
    const int lr = lane & 15;
    const int lq = lane >> 4;

    const int ar = tid >> 3;
    const int ac = tid & 7;
    const int apx = ac ^ (ar & 7);
    const unsigned short* aptr[4];
#pragma unroll
    for (int i = 0; i < 4; i++)
        aptr[i] = hbuf + (size_t)rowp[ar + i * 32] * INTER + ac * 8;

    const float* bptr = wdp + (size_t)e * INTER * HIDDEN + n0 + lane;

    f32x4 acc[4][2];
    const f32x4 z4 = {0.f, 0.f, 0.f, 0.f};
#pragma unroll
    for (int a = 0; a < 4; a++)
#pragma unroll
        for (int b = 0; b < 2; b++) acc[a][b] = z4;

    uint4 pa[4];
    float pb[2][8];

    auto loadAB = [&](int k0) {
#pragma unroll
        for (int i = 0; i < 4; i++) pa[i] = *(const uint4*)(aptr[i] + k0);
#pragma unroll
        for (int i = 0; i < 2; i++) {
            const int c = i * 4 + wid;
            const float* src = bptr + (size_t)(k0 + c * 8) * HIDDEN;
#pragma unroll
            for (int j = 0; j < 8; j++) pb[i][j] = src[(size_t)j * HIDDEN];
        }
    };

    loadAB(0);
    for (int k0 = 0; k0 < INTER; k0 += BK) {
#pragma unroll
        for (int i = 0; i < 4; i++)
            *(uint4*)&As[(ar + i * 32) * ROWU + apx * 8] = pa[i];
#pragma unroll
        for (int i = 0; i < 2; i++) {
            const int c = i * 4 + wid;
            pack8(pb[i], &Bs[lane * ROWU + (c ^ (lane & 7)) * 8]);
        }
        __syncthreads();
        if (k0 + BK < INTER) loadAB(k0 + BK);

#pragma unroll
        for (int ks = 0; ks < 2; ks++) {
            bf16x8 af[4], bb[2];
#pragma unroll
            for (int tm = 0; tm < 4; tm++)
                af[tm] = *(const bf16x8*)&As[(wm + tm * 16 + lr) * ROWU + ((ks * 4 + lq) ^ (lr & 7)) * 8];
#pragma unroll
            for (int tn = 0; tn < 2; tn++)
                bb[tn] = *(const bf16x8*)&Bs[(wn + tn * 16 + lr) * ROWU + ((ks * 4 + lq) ^ (lr & 7)) * 8];
#pragma unroll
            for (int tm = 0; tm < 4; tm++)
#pragma unroll
                for (int tn = 0; tn < 2; tn++)
                    acc[tm][tn] = __builtin_amdgcn_mfma_f32_16x16x32_bf16(af[tm], bb[tn], acc[tm][tn], 0, 0, 0);
        }
        __syncthreads();
    }

#pragma unroll
    for (int tm = 0; tm < 4; tm++)
#pragma unroll
        for (int tn = 0; tn < 2; tn++)
#pragma unroll
            for (int r = 0; r < 4; r++) {
                const int rowL = wm + tm * 16 + lq * 4 + r;
                const int slot = m0 + rowL;
                if (slot < ne) {
                    const int t = rowp[rowL] >> 1;
                    const float w = roww[rowL];
                    atomicAdd(&out[(size_t)t * HIDDEN + n0 + wn + tn * 16 + lr],
                              w * acc[tm][tn][r]);
                }
            }
}

extern "C" void kernel_launch(void* const* d_in, const int* in_sizes, int n_in,
                              void* d_out, int out_size, void* d_ws, size_t ws_size,
                              hipStream_t stream) {
    const float* x   = (const float*)d_in[0];
    const float* wg  = (const float*)d_in[1];
    const float* wgp = (const float*)d_in[2];
    const float* wup = (const float*)d_in[3];
    const float* wdp = (const float*)d_in[4];
    float* out = (float*)d_out;

    char* ws = (char*)d_ws;
    int*   cnt  = (int*)ws;                              // 256 B region
    int*   tok  = (int*)(ws + 256);                      // 16*2048*4 = 131072
    float* wts  = (float*)(ws + 256 + 131072);           // 131072
    unsigned short* xbf  = (unsigned short*)(ws + 262400);            // 2048*2048*2 = 8 MB
    unsigned short* hbuf = (unsigned short*)(ws + 262400 + 8388608);  // 4096*1408*2 = 11.5 MB

    hipMemsetAsync(cnt, 0, NEXP * sizeof(int), stream);
    hipMemsetAsync(out, 0, (size_t)TOKENS * HIDDEN * sizeof(float), stream);

    router_kernel<<<dim3(TOKENS), dim3(64), 0, stream>>>(x, wg, cnt, tok, wts, xbf);

    dim3 g1(INTER / 64, TOKENS / 128, NEXP);    // (22, 16, 16), early-exit on cnt
    gemm1_kernel<<<g1, dim3(256), 0, stream>>>(xbf, wgp, wup, cnt, tok, hbuf);

    dim3 g2(HIDDEN / 64, TOKENS / 128, NEXP);   // (32, 16, 16)
    gemm2_kernel<<<g2, dim3(256), 0, stream>>>(hbuf, wdp, cnt, tok, wts, out);
}

// Round 3
// 687.051 us; speedup vs baseline: 1.3448x; 1.3448x over previous
//
#include <hip/hip_runtime.h>
#include <stdint.h>

#define TOKENS 2048
#define HIDDEN 2048
#define INTER  1408
#define NEXP   16
#define BK     64      // K-tile; LDS rows are 64 ushorts = 128 B, 8 x 16B chunks

using bf16x8 = __attribute__((ext_vector_type(8))) __bf16;
using f32x8  = __attribute__((ext_vector_type(8))) float;
using f32x4  = __attribute__((ext_vector_type(4))) float;

__device__ __forceinline__ unsigned short bf16bits(float f) {
    union { __bf16 h; unsigned short u; } cv;
    cv.h = (__bf16)f;
    return cv.u;
}

__device__ __forceinline__ void cvt_store8(const f32x8& s, unsigned short* dst) {
    bf16x8 v;
#pragma unroll
    for (int j = 0; j < 8; j++) v[j] = (__bf16)s[j];
    *(bf16x8*)dst = v;
}

// ---------------- router: logits -> sigmoid -> top2 -> expert lists; also x -> bf16 ----------------
__global__ __launch_bounds__(64) void router_kernel(
    const float* __restrict__ x, const float* __restrict__ wg,
    int* __restrict__ cnt, int* __restrict__ tok, float* __restrict__ wts,
    unsigned short* __restrict__ xbf)
{
    const int t = blockIdx.x;
    const int lane = threadIdx.x;
    float acc[NEXP];
#pragma unroll
    for (int e = 0; e < NEXP; e++) acc[e] = 0.f;
    const float* xr = x + (size_t)t * HIDDEN;
    unsigned short* xbr = xbf + (size_t)t * HIDDEN;
    for (int h = lane; h < HIDDEN; h += 64) {
        const float xv = xr[h];
        xbr[h] = bf16bits(xv);
        const float* wr = wg + (size_t)h * NEXP;
#pragma unroll
        for (int e = 0; e < NEXP; e++) acc[e] += xv * wr[e];
    }
#pragma unroll
    for (int off = 32; off > 0; off >>= 1) {
#pragma unroll
        for (int e = 0; e < NEXP; e++) acc[e] += __shfl_down(acc[e], off, 64);
    }
    if (lane == 0) {
        float s[NEXP];
#pragma unroll
        for (int e = 0; e < NEXP; e++) s[e] = 1.f / (1.f + __expf(-acc[e]));
        int i0 = 0;
#pragma unroll
        for (int e = 1; e < NEXP; e++) if (s[e] > s[i0]) i0 = e;
        int i1 = (i0 == 0) ? 1 : 0;
#pragma unroll
        for (int e = 0; e < NEXP; e++) if (e != i0 && s[e] > s[i1]) i1 = e;
        float w0 = s[i0], w1 = s[i1];
        const float inv = 1.f / (w0 + w1);
        w0 *= inv; w1 *= inv;
        const int s0 = atomicAdd(&cnt[i0], 1);
        tok[i0 * TOKENS + s0] = t * 2;
        wts[i0 * TOKENS + s0] = w0;
        const int s1 = atomicAdd(&cnt[i1], 1);
        tok[i1 * TOKENS + s1] = t * 2 + 1;
        wts[i1 * TOKENS + s1] = w1;
    }
}

// B prefetch: 8 strided fp32 loads into a named f32x8 (no arrays, no lambda -> no scratch)
#define LOADVEC8(dstv, baseptr, koff, ldstride)                         \
    do {                                                                \
        const float* _s = (baseptr) + (size_t)(koff) * (ldstride);      \
        _Pragma("unroll")                                               \
        for (int _j = 0; _j < 8; _j++) dstv[_j] = _s[(size_t)_j * (ldstride)]; \
    } while (0)

// ---------------- gemm1: h = silu(Xe @ Wg) * (Xe @ Wu), bf16 out ----------------
// grid: (INTER/64, TOKENS/128, NEXP), block 256. BM=128 BN=64 BK=64.
__global__ __launch_bounds__(256, 2) void gemm1_kernel(
    const unsigned short* __restrict__ xbf, const float* __restrict__ wgp,
    const float* __restrict__ wup, const int* __restrict__ cnt,
    const int* __restrict__ tok, unsigned short* __restrict__ hbuf)
{
    const int e = blockIdx.z;
    const int ne = cnt[e];
    const int m0 = blockIdx.y * 128;
    if (m0 >= ne) return;
    const int n0 = blockIdx.x * 64;

    __shared__ __align__(16) unsigned short As[128 * 64];
    __shared__ __align__(16) unsigned short Bs[2][64 * 64];
    __shared__ int rowp[128];

    const int tid = threadIdx.x;
    if (tid < 128) {
        const int slot = m0 + tid;
        rowp[tid] = tok[e * TOKENS + (slot < ne ? slot : ne - 1)];
    }
    __syncthreads();

    const int lane = tid & 63;
    const int w    = tid >> 6;
    const int wm = (w >> 1) * 64;
    const int wn = (w & 1) * 32;
    const int lr = lane & 15;
    const int lq = lane >> 4;

    // ---- A staging: 4 rows/thread, 16B chunk ac, swizzled slot ac^(row&7) ----
    const int ac  = tid & 7;
    const int ar0 = tid >> 3;                 // 0..31
    const unsigned short* asrc0 = xbf + (size_t)(rowp[ar0     ] >> 1) * HIDDEN + ac * 8;
    const unsigned short* asrc1 = xbf + (size_t)(rowp[ar0 + 32] >> 1) * HIDDEN + ac * 8;
    const unsigned short* asrc2 = xbf + (size_t)(rowp[ar0 + 64] >> 1) * HIDDEN + ac * 8;
    const unsigned short* asrc3 = xbf + (size_t)(rowp[ar0 + 96] >> 1) * HIDDEN + ac * 8;
    const int asw = (ac ^ (ar0 & 7)) * 8;     // row&7 identical for all 4 rows
    unsigned short* adst0 = &As[(ar0     ) * 64 + asw];
    unsigned short* adst1 = &As[(ar0 + 32) * 64 + asw];
    unsigned short* adst2 = &As[(ar0 + 64) * 64 + asw];
    unsigned short* adst3 = &As[(ar0 + 96) * 64 + asw];

    // ---- B staging: n=lane, kc = w and w+4; transposed [n][k] with swizzle ----
    const int bn = lane;
    const int bk = w;                          // 0..3
    const float* bsg = wgp + (size_t)e * HIDDEN * INTER + n0 + bn;
    const float* bsu = wup + (size_t)e * HIDDEN * INTER + n0 + bn;
    unsigned short* bdg0 = &Bs[0][bn * 64 + ((bk    ) ^ (bn & 7)) * 8];
    unsigned short* bdg1 = &Bs[0][bn * 64 + ((bk + 4) ^ (bn & 7)) * 8];
    unsigned short* bdu0 = &Bs[1][bn * 64 + ((bk    ) ^ (bn & 7)) * 8];
    unsigned short* bdu1 = &Bs[1][bn * 64 + ((bk + 4) ^ (bn & 7)) * 8];

    f32x4 accg[4][2], accu[4][2];
    const f32x4 z4 = {0.f, 0.f, 0.f, 0.f};
#pragma unroll
    for (int a = 0; a < 4; a++)
#pragma unroll
        for (int b = 0; b < 2; b++) { accg[a][b] = z4; accu[a][b] = z4; }

    f32x8 pg0, pg1, pu0, pu1;                  // B prefetch (stays in VGPRs)
    LOADVEC8(pg0, bsg, bk * 8,        INTER);
    LOADVEC8(pg1, bsg, bk * 8 + 32,   INTER);
    LOADVEC8(pu0, bsu, bk * 8,        INTER);
    LOADVEC8(pu1, bsu, bk * 8 + 32,   INTER);

    for (int k0 = 0; k0 < HIDDEN; k0 += BK) {
        // stage A (bf16 copies) and B (from prefetched regs)
        const uint4 a0 = *(const uint4*)(asrc0 + k0);
        const uint4 a1 = *(const uint4*)(asrc1 + k0);
        const uint4 a2 = *(const uint4*)(asrc2 + k0);
        const uint4 a3 = *(const uint4*)(asrc3 + k0);
        *(uint4*)adst0 = a0;
        *(uint4*)adst1 = a1;
        *(uint4*)adst2 = a2;
        *(uint4*)adst3 = a3;
        cvt_store8(pg0, bdg0);
        cvt_store8(pg1, bdg1);
        cvt_store8(pu0, bdu0);
        cvt_store8(pu1, bdu1);
        __syncthreads();

        if (k0 + BK < HIDDEN) {               // prefetch next B tile; overlaps MFMA
            LOADVEC8(pg0, bsg, k0 + BK + bk * 8,      INTER);
            LOADVEC8(pg1, bsg, k0 + BK + bk * 8 + 32, INTER);
            LOADVEC8(pu0, bsu, k0 + BK + bk * 8,      INTER);
            LOADVEC8(pu1, bsu, k0 + BK + bk * 8 + 32, INTER);
        }

#pragma unroll
        for (int ks = 0; ks < 2; ks++) {
            bf16x8 af[4], bg[2], bu[2];
#pragma unroll
            for (int tm = 0; tm < 4; tm++) {
                const int r = wm + tm * 16 + lr;
                af[tm] = *(const bf16x8*)&As[r * 64 + (((ks * 4 + lq) ^ (lr & 7)) * 8)];
            }
#pragma unroll
            for (int tn = 0; tn < 2; tn++) {
                const int r = wn + tn * 16 + lr;
                const int off = r * 64 + (((ks * 4 + lq) ^ (lr & 7)) * 8);
                bg[tn] = *(const bf16x8*)&Bs[0][off];
                bu[tn] = *(const bf16x8*)&Bs[1][off];
            }
#pragma unroll
            for (int tm = 0; tm < 4; tm++)
#pragma unroll
                for (int tn = 0; tn < 2; tn++) {
                    accg[tm][tn] = __builtin_amdgcn_mfma_f32_16x16x32_bf16(af[tm], bg[tn], accg[tm][tn], 0, 0, 0);
                    accu[tm][tn] = __builtin_amdgcn_mfma_f32_16x16x32_bf16(af[tm], bu[tn], accu[tm][tn], 0, 0, 0);
                }
        }
        __syncthreads();
    }

    // epilogue: h = silu(g)*u -> bf16, scattered by pair id
#pragma unroll
    for (int tm = 0; tm < 4; tm++)
#pragma unroll
        for (int tn = 0; tn < 2; tn++)
#pragma unroll
            for (int r = 0; r < 4; r++) {
                const int rowL = wm + tm * 16 + lq * 4 + r;
                const int slot = m0 + rowL;
                if (slot < ne) {
                    const int p = rowp[rowL];
                    const int col = n0 + wn + tn * 16 + lr;
                    const float g = accg[tm][tn][r];
                    const float u = accu[tm][tn][r];
                    const float hv = g * u / (1.f + __expf(-g));
                    hbuf[(size_t)p * INTER + col] = bf16bits(hv);
                }
            }
}

// ---------------- gemm2: out[t] += w * (h_e @ Wd[e]) ----------------
// grid: (HIDDEN/64, TOKENS/128, NEXP), block 256. BM=128 BN=64 BK=64, K=1408.
__global__ __launch_bounds__(256, 2) void gemm2_kernel(
    const unsigned short* __restrict__ hbuf, const float* __restrict__ wdp,
    const int* __restrict__ cnt, const int* __restrict__ tok,
    const float* __restrict__ wts, float* __restrict__ out)
{
    const int e = blockIdx.z;
    const int ne = cnt[e];
    const int m0 = blockIdx.y * 128;
    if (m0 >= ne) return;
    const int n0 = blockIdx.x * 64;

    __shared__ __align__(16) unsigned short As[128 * 64];
    __shared__ __align__(16) unsigned short Bs[64 * 64];
    __shared__ int rowp[128];
    __shared__ float roww[128];

    const int tid = threadIdx.x;
    if (tid < 128) {
        const int slot = m0 + tid;
        const int cs = slot < ne ? slot : ne - 1;
        rowp[tid] = tok[e * TOKENS + cs];
        roww[tid] = wts[e * TOKENS + cs];
    }
    __syncthreads();

    const int lane = tid & 63;
    const int w    = tid >> 6;
    const int wm = (w >> 1) * 64;
    const int wn = (w & 1) * 32;
    const int lr = lane & 15;
    const int lq = lane >> 4;

    const int ac  = tid & 7;
    const int ar0 = tid >> 3;
    const unsigned short* asrc0 = hbuf + (size_t)rowp[ar0     ] * INTER + ac * 8;
    const unsigned short* asrc1 = hbuf + (size_t)rowp[ar0 + 32] * INTER + ac * 8;
    const unsigned short* asrc2 = hbuf + (size_t)rowp[ar0 + 64] * INTER + ac * 8;
    const unsigned short* asrc3 = hbuf + (size_t)rowp[ar0 + 96] * INTER + ac * 8;
    const int asw = (ac ^ (ar0 & 7)) * 8;
    unsigned short* adst0 = &As[(ar0     ) * 64 + asw];
    unsigned short* adst1 = &As[(ar0 + 32) * 64 + asw];
    unsigned short* adst2 = &As[(ar0 + 64) * 64 + asw];
    unsigned short* adst3 = &As[(ar0 + 96) * 64 + asw];

    const int bn = lane;
    const int bk = w;
    const float* bsd = wdp + (size_t)e * INTER * HIDDEN + n0 + bn;
    unsigned short* bdd0 = &Bs[bn * 64 + ((bk    ) ^ (bn & 7)) * 8];
    unsigned short* bdd1 = &Bs[bn * 64 + ((bk + 4) ^ (bn & 7)) * 8];

    f32x4 acc[4][2];
    const f32x4 z4 = {0.f, 0.f, 0.f, 0.f};
#pragma unroll
    for (int a = 0; a < 4; a++)
#pragma unroll
        for (int b = 0; b < 2; b++) acc[a][b] = z4;

    f32x8 pd0, pd1;
    LOADVEC8(pd0, bsd, bk * 8,      HIDDEN);
    LOADVEC8(pd1, bsd, bk * 8 + 32, HIDDEN);

    for (int k0 = 0; k0 < INTER; k0 += BK) {
        const uint4 a0 = *(const uint4*)(asrc0 + k0);
        const uint4 a1 = *(const uint4*)(asrc1 + k0);
        const uint4 a2 = *(const uint4*)(asrc2 + k0);
        const uint4 a3 = *(const uint4*)(asrc3 + k0);
        *(uint4*)adst0 = a0;
        *(uint4*)adst1 = a1;
        *(uint4*)adst2 = a2;
        *(uint4*)adst3 = a3;
        cvt_store8(pd0, bdd0);
        cvt_store8(pd1, bdd1);
        __syncthreads();

        if (k0 + BK < INTER) {
            LOADVEC8(pd0, bsd, k0 + BK + bk * 8,      HIDDEN);
            LOADVEC8(pd1, bsd, k0 + BK + bk * 8 + 32, HIDDEN);
        }

#pragma unroll
        for (int ks = 0; ks < 2; ks++) {
            bf16x8 af[4], bb[2];
#pragma unroll
            for (int tm = 0; tm < 4; tm++) {
                const int r = wm + tm * 16 + lr;
                af[tm] = *(const bf16x8*)&As[r * 64 + (((ks * 4 + lq) ^ (lr & 7)) * 8)];
            }
#pragma unroll
            for (int tn = 0; tn < 2; tn++) {
                const int r = wn + tn * 16 + lr;
                bb[tn] = *(const bf16x8*)&Bs[r * 64 + (((ks * 4 + lq) ^ (lr & 7)) * 8)];
            }
#pragma unroll
            for (int tm = 0; tm < 4; tm++)
#pragma unroll
                for (int tn = 0; tn < 2; tn++)
                    acc[tm][tn] = __builtin_amdgcn_mfma_f32_16x16x32_bf16(af[tm], bb[tn], acc[tm][tn], 0, 0, 0);
        }
        __syncthreads();
    }

#pragma unroll
    for (int tm = 0; tm < 4; tm++)
#pragma unroll
        for (int tn = 0; tn < 2; tn++)
#pragma unroll
            for (int r = 0; r < 4; r++) {
                const int rowL = wm + tm * 16 + lq * 4 + r;
                const int slot = m0 + rowL;
                if (slot < ne) {
                    const int t = rowp[rowL] >> 1;
                    const float wv = roww[rowL];
                    atomicAdd(&out[(size_t)t * HIDDEN + n0 + wn + tn * 16 + lr],
                              wv * acc[tm][tn][r]);
                }
            }
}

extern "C" void kernel_launch(void* const* d_in, const int* in_sizes, int n_in,
                              void* d_out, int out_size, void* d_ws, size_t ws_size,
                              hipStream_t stream) {
    const float* x   = (const float*)d_in[0];
    const float* wg  = (const float*)d_in[1];
    const float* wgp = (const float*)d_in[2];
    const float* wup = (const float*)d_in[3];
    const float* wdp = (const float*)d_in[4];
    float* out = (float*)d_out;

    char* ws = (char*)d_ws;
    int*   cnt  = (int*)ws;                              // 256 B region
    int*   tok  = (int*)(ws + 256);                      // 16*2048*4 = 131072
    float* wts  = (float*)(ws + 256 + 131072);           // 131072
    unsigned short* xbf  = (unsigned short*)(ws + 262400);            // 2048*2048*2 = 8 MB
    unsigned short* hbuf = (unsigned short*)(ws + 262400 + 8388608);  // 4096*1408*2 = 11.5 MB

    hipMemsetAsync(cnt, 0, NEXP * sizeof(int), stream);
    hipMemsetAsync(out, 0, (size_t)TOKENS * HIDDEN * sizeof(float), stream);

    router_kernel<<<dim3(TOKENS), dim3(64), 0, stream>>>(x, wg, cnt, tok, wts, xbf);

    dim3 g1(INTER / 64, TOKENS / 128, NEXP);    // (22, 16, 16), early-exit on cnt
    gemm1_kernel<<<g1, dim3(256), 0, stream>>>(xbf, wgp, wup, cnt, tok, hbuf);

    dim3 g2(HIDDEN / 64, TOKENS / 128, NEXP);   // (32, 16, 16)
    gemm2_kernel<<<g2, dim3(256), 0, stream>>>(hbuf, wdp, cnt, tok, wts, out);
}